// Round 3
// baseline (96616.302 us; speedup 1.0000x reference)
//
#include <hip/hip_runtime.h>
#include <hip/hip_bf16.h>

// Persistent-kernel seq2seq (enc LSTM -> attn decoder -> CE loss) for MI355X.
// 256 WGs x 256 thr, 1 WG/CU (152KB LDS).
// R3: fence-free rowgroup barriers. Cross-WG data goes through device-scope
// RELAXED atomics (sc0/sc1 bypass) so L2 stays warm (weights/enc_hs resident);
// no buffer_inv per barrier. Full agent fences only at 3 grid barriers.

#define NWG 256
#define NT  256

typedef unsigned short u16;
typedef unsigned int   u32;
typedef unsigned long long u64;
typedef __attribute__((ext_vector_type(4))) float f4;
typedef __attribute__((ext_vector_type(8))) short s8;

constexpr int Bv = 128, Lc = 512, Le = 512, Hd = 512, Vc = 128;
constexpr int KE = 640;   // enc gate GEMM K = V + H
constexpr int KD = 1152;  // dec gate GEMM K = V + H + H

// ---- workspace layout (bytes) ----
constexpr size_t O_WENC = 4096;                                  // bf16 [2048][640]
constexpr size_t O_WDEC = O_WENC + (size_t)2048*KE*2;            // bf16 [2048][1152]
constexpr size_t O_ATTW = O_WDEC + (size_t)2048*KD*2;            // bf16 [512][512]
constexpr size_t O_OUTW = O_ATTW + (size_t)512*512*2;            // bf16 [512][1024]
constexpr size_t O_VOCW = O_OUTW + (size_t)512*1024*2;           // bf16 [128][512]
constexpr size_t O_BE   = O_VOCW + (size_t)128*512*2;            // f32 [2048]
constexpr size_t O_BD   = O_BE + 2048*4;                         // f32 [2048]
constexpr size_t O_H    = O_BD + 2048*4;                         // bf16 [2][128][512] ping-pong
constexpr size_t O_VPRV = O_H + (size_t)2*128*512*2;             // bf16 [128][512]
constexpr size_t O_Q    = O_VPRV + (size_t)128*512*2;            // f32 [128][512]
constexpr size_t O_ATTN = O_Q + (size_t)128*512*4;               // bf16 [128][512]
constexpr size_t O_TANH = O_ATTN + (size_t)128*512*2;            // bf16 [128][512]
constexpr size_t O_PFX  = O_TANH + (size_t)128*512*2;            // u32 [128][512]
constexpr size_t O_CNT  = O_PFX + (size_t)128*512*4;             // u32 [128]
constexpr size_t O_PM   = O_CNT + 512;                           // f32 [256] by lid
constexpr size_t O_PS   = O_PM + 1024;                           // f32 [256] by lid
constexpr size_t O_PACC = O_PS + 1024;                           // f32 [256][512] by lid
constexpr size_t O_LOSS = O_PACC + (size_t)256*512*4;            // f32 [2]
constexpr size_t O_ENC  = O_LOSS + 256;                          // bf16 [128][512][512] compacted
constexpr size_t WS_NEED= O_ENC + (size_t)128*512*512*2;         // ~78 MB

// ---- LDS layout ----
constexpr int SM_U     = 64*KD*2;         // 147456: weight slice region end
constexpr int SM_BYTES = SM_U + 8192;

struct P {
  const float *C; const int *Cpad; const int *E; const float *Eemb;
  const float *eWih,*eWhh,*ebih,*ebhh;
  const float *dWih,*dWhh,*dbih,*dbhh;
  const float *attW,*outW,*outb,*vocW,*vocb;
  char* ws; float* out;
};

__device__ inline u16 f2bf(float x){
  u32 u = __float_as_uint(x);
  u32 r = (u + 0x7fffu + ((u>>16)&1u)) >> 16;
  return (u16)r;
}
__device__ inline float bf2f(u16 b){ return __uint_as_float(((u32)b)<<16); }
__device__ inline float sigm(float x){ return 1.f/(1.f+expf(-x)); }

__device__ inline f4 MM(s8 a, s8 b, f4 c){
  return __builtin_amdgcn_mfma_f32_16x16x32_bf16(a, b, c, 0, 0, 0);
}

// ---- device-scope (MALL-coherent) access helpers: relaxed atomics compile
// to sc0/sc1 cache-bypass loads / write-through stores; no fences needed. ----
__device__ inline u64 ld64a(const void* p){
  return __hip_atomic_load((const u64*)p, __ATOMIC_RELAXED, __HIP_MEMORY_SCOPE_AGENT);
}
__device__ inline float ld32a(const void* p){
  return __hip_atomic_load((const float*)p, __ATOMIC_RELAXED, __HIP_MEMORY_SCOPE_AGENT);
}
__device__ inline void st64a(void* p, u64 v){
  __hip_atomic_store((u64*)p, v, __ATOMIC_RELAXED, __HIP_MEMORY_SCOPE_AGENT);
}
__device__ inline void st32a(void* p, u32 v){
  __hip_atomic_store((u32*)p, v, __ATOMIC_RELAXED, __HIP_MEMORY_SCOPE_AGENT);
}
__device__ inline void st32af(void* p, float v){
  __hip_atomic_store((float*)p, v, __ATOMIC_RELAXED, __HIP_MEMORY_SCOPE_AGENT);
}
__device__ inline s8 ld16a(const void* p){
  union { u64 q[2]; s8 v; } u;
  u.q[0] = ld64a(p);
  u.q[1] = ld64a((const char*)p + 8);
  return u.v;
}

// on-the-fly f32 -> bf16 A fragment (8 contiguous k), cached read
__device__ inline s8 cvt8(const float* p){
  f4 u = *(const f4*)p, v = *(const f4*)(p+4);
  s8 r;
  r[0]=(short)f2bf(u[0]); r[1]=(short)f2bf(u[1]); r[2]=(short)f2bf(u[2]); r[3]=(short)f2bf(u[3]);
  r[4]=(short)f2bf(v[0]); r[5]=(short)f2bf(v[1]); r[6]=(short)f2bf(v[2]); r[7]=(short)f2bf(v[3]);
  return r;
}

// B fragment read from XOR-swizzled LDS weight slice [64][K]
__device__ inline s8 ldsB(const char* sm, int K, int srow, int k){
  int byte = srow*(K*2) + k*2;
  byte ^= (srow&7)<<4;
  return *(const s8*)(sm + byte);
}

__device__ inline float wredmax(float v){
  #pragma unroll
  for (int m=32;m;m>>=1) v = fmaxf(v, __shfl_xor(v,m,64));
  return v;
}
__device__ inline float wredsum(float v){
  #pragma unroll
  for (int m=32;m;m>>=1) v += __shfl_xor(v,m,64);
  return v;
}

extern "C" __global__ void __launch_bounds__(NT,1) k_main(P p)
{
  extern __shared__ char sm[];
  const int wg = blockIdx.x, tid = threadIdx.x;
  const int gt = wg*NT + tid;

  const int rg = wg & 7, cg = wg >> 3;
  const int lid = rg*32 + cg;

  char* ws = p.ws;
  u32*  barAll = (u32*)ws;
  u32*  barRG  = (u32*)(ws + 256 + rg*128);
  u16*  wenc = (u16*)(ws + O_WENC);
  u16*  wdec = (u16*)(ws + O_WDEC);
  u16*  attw = (u16*)(ws + O_ATTW);
  u16*  outw = (u16*)(ws + O_OUTW);
  u16*  vocw = (u16*)(ws + O_VOCW);
  float* be  = (float*)(ws + O_BE);
  float* bd  = (float*)(ws + O_BD);
  u16*  hbf  = (u16*)(ws + O_H);
  u16*  vpv  = (u16*)(ws + O_VPRV);
  float* qg  = (float*)(ws + O_Q);
  u16*  attnb= (u16*)(ws + O_ATTN);
  u16*  tnh  = (u16*)(ws + O_TANH);
  u32*  pfx  = (u32*)(ws + O_PFX);
  u32*  cntp = (u32*)(ws + O_CNT);
  float* pm  = (float*)(ws + O_PM);
  float* ps  = (float*)(ws + O_PS);
  float* pacc= (float*)(ws + O_PACC);
  float* losp= (float*)(ws + O_LOSS);
  u16*  encc = (u16*)(ws + O_ENC);

  u32 genA = 0, genG = 0;

  // Full-fence grid barrier (3 uses total): release(wbl2) + acquire(inv).
  auto GBall = [&](){
    genA++;
    u32 target = genA*(u32)NWG;
    __syncthreads();
    if (tid == 0){
      __builtin_amdgcn_fence(__ATOMIC_RELEASE, "agent");
      __hip_atomic_fetch_add(barAll, 1u, __ATOMIC_RELAXED, __HIP_MEMORY_SCOPE_AGENT);
      while (__hip_atomic_load(barAll, __ATOMIC_RELAXED, __HIP_MEMORY_SCOPE_AGENT) < target)
        __builtin_amdgcn_s_sleep(1);
      __builtin_amdgcn_fence(__ATOMIC_ACQUIRE, "agent");
    }
    __syncthreads();
  };

  // Fence-free rowgroup barrier (32 WGs). Shared data moves via relaxed
  // device-scope atomics (bypass), so NO cache invalidate is needed here.
  auto RGB = [&](){
    genG++;
    u32 target = genG*32u;
    __syncthreads();
    if (tid == 0){
      __hip_atomic_fetch_add(barRG, 1u, __ATOMIC_RELAXED, __HIP_MEMORY_SCOPE_AGENT);
      while (__hip_atomic_load(barRG, __ATOMIC_RELAXED, __HIP_MEMORY_SCOPE_AGENT) < target)
        __builtin_amdgcn_s_sleep(1);
      __builtin_amdgcn_fence(__ATOMIC_ACQUIRE, "workgroup");  // compiler ordering only
    }
    __syncthreads();
  };

  // ================= phase 0: pack/convert/init =================
  for (int i = gt; i < 2048*KE; i += NWG*NT){
    int row = i / KE, k = i - row*KE;
    float v = (k < 128) ? p.eWih[row*128 + k] : p.eWhh[row*512 + (k-128)];
    wenc[i] = f2bf(v);
  }
  for (int i = gt; i < 2048*KD; i += NWG*NT){
    int row = i / KD, k = i - row*KD;
    float v = (k < 640) ? p.dWih[row*640 + k] : p.dWhh[row*512 + (k-640)];
    wdec[i] = f2bf(v);
  }
  for (int i = gt; i < 512*512;  i += NWG*NT) attw[i] = f2bf(p.attW[i]);
  for (int i = gt; i < 512*1024; i += NWG*NT) outw[i] = f2bf(p.outW[i]);
  for (int i = gt; i < 128*512;  i += NWG*NT) vocw[i] = f2bf(p.vocW[i]);
  for (int i = gt; i < 2048;     i += NWG*NT){ be[i] = p.ebih[i]+p.ebhh[i]; bd[i] = p.dbih[i]+p.dbhh[i]; }
  { u32* hz = (u32*)hbf; for (int i = gt; i < 65536; i += NWG*NT) hz[i] = 0; }
  { u32* vz = (u32*)vpv; for (int i = gt; i < 32768; i += NWG*NT) vz[i] = 0; }
  if (gt == 0){ losp[0] = 0.f; losp[1] = 0.f; }
  if (wg < 128){
    int* padl = (int*)(sm + SM_U);
    for (int i = tid; i < 512; i += NT) padl[i] = p.Cpad[wg*512 + i];
    __syncthreads();
    if (tid == 0){
      u32 run = 0;
      for (int tt = 0; tt < 512; tt++){ pfx[wg*512+tt] = run; if (padl[tt] == 0) run++; }
      cntp[wg] = run;
    }
    __syncthreads();
  }
  GBall();

  // persistent ownership
  const int l  = tid & 63, wv = tid >> 6;
  const int n2 = wv >> 1, k2 = wv & 1;
  const int kl = (l>>4) << 3;
  const int ar = rg*16 + (l&15);
  float cst = 0.f;
  float accN = 0.f, accC = 0.f;

  // ================= encoder =================
  { // preload enc weight slice to LDS (XOR swizzle)
    const int chunks = KE/8;
    for (int idx = tid; idx < 64*chunks; idx += NT){
      int s = idx / chunks, cc = idx - s*chunks;
      int grow = (s>>4)*512 + cg*16 + (s&15);
      uint4 v = *(const uint4*)(wenc + (size_t)grow*KE + cc*8);
      int byte = s*(KE*2) + cc*16; byte ^= (s&7)<<4;
      *(uint4*)(sm + byte) = v;
    }
  }
  __syncthreads();

  for (int t = 0; t < Lc; t++){
    const u16* hold = hbf + (t&1)*Bv*Hd;
    u16* hnew       = hbf + ((t+1)&1)*Bv*Hd;
    // prefetch all A fragments (bypass for h; cached for C)
    s8 a[10];
    #pragma unroll
    for (int ks = 0; ks < 10; ks++){
      int k = k2*320 + ks*32 + kl;
      if (k < 128) a[ks] = cvt8(p.C + ((size_t)ar*Lc + t)*Vc + k);
      else         a[ks] = ld16a(hold + ar*Hd + (k-128));
    }
    f4 acc0 = {0.f,0.f,0.f,0.f}, acc1 = {0.f,0.f,0.f,0.f};
    #pragma unroll
    for (int ks = 0; ks < 10; ks++){
      int k = k2*320 + ks*32 + kl;
      acc0 = MM(a[ks], ldsB(sm, KE, (n2*2+0)*16 + (l&15), k), acc0);
      acc1 = MM(a[ks], ldsB(sm, KE, (n2*2+1)*16 + (l&15), k), acc1);
    }
    float* exch = (float*)(sm + SM_U);
    #pragma unroll
    for (int r = 0; r < 4; r++){
      int row = ((l>>4)<<2) + r;
      exch[((k2*4 + n2*2+0)*16 + row)*16 + (l&15)] = acc0[r];
      exch[((k2*4 + n2*2+1)*16 + row)*16 + (l&15)] = acc1[r];
    }
    __syncthreads();
    {
      int row = tid >> 4, u = tid & 15;
      int gb = cg*16 + u;
      float gi = exch[((0)*16+row)*16+u] + exch[((4)*16+row)*16+u] + be[0*512+gb];
      float gf = exch[((1)*16+row)*16+u] + exch[((5)*16+row)*16+u] + be[1*512+gb];
      float gg = exch[((2)*16+row)*16+u] + exch[((6)*16+row)*16+u] + be[2*512+gb];
      float go = exch[((3)*16+row)*16+u] + exch[((7)*16+row)*16+u] + be[3*512+gb];
      float fi = sigm(gi), ff = sigm(gf), fg = tanhf(gg), fo = sigm(go);
      cst = ff*cst + fi*fg;
      float hn = fo * tanhf(cst);
      int b = rg*16 + row;
      u32 hb = f2bf(hn);
      u32 nb = __shfl_xor((int)hb, 1, 64);
      if ((tid & 1) == 0){
        u32 pk = hb | (nb << 16);
        st32a(hnew + b*Hd + gb, pk);
        if (p.Cpad[b*Lc + t] == 0){
          u32 pos = pfx[b*Lc + t];
          st32a(encc + ((size_t)b*Lc + pos)*Hd + gb, pk);
        }
      }
    }
    RGB();
  }

  GBall();   // enc->dec transition: flush + invalidate once so decoder's
             // CACHED encc/pfx reads are guaranteed fresh.

  // ================= decoder =================
  { // preload dec weight slice
    const int chunks = KD/8;
    for (int idx = tid; idx < 64*chunks; idx += NT){
      int s = idx / chunks, cc = idx - s*chunks;
      int grow = (s>>4)*512 + cg*16 + (s&15);
      uint4 v = *(const uint4*)(wdec + (size_t)grow*KD + cc*8);
      int byte = s*(KD*2) + cc*16; byte ^= (s&7)<<4;
      *(uint4*)(sm + byte) = v;
    }
  }
  __syncthreads();

  for (int t = 0; t < Le-1; t++){
    const u16* hold = hbf + (t&1)*Bv*Hd;
    u16* hnew       = hbf + ((t+1)&1)*Bv*Hd;

    // ---- S1: gates GEMM + cell ----
    {
      s8 a[18];
      #pragma unroll
      for (int ks = 0; ks < 18; ks++){
        int k = k2*576 + ks*32 + kl;
        if (k < 128)      a[ks] = cvt8(p.Eemb + ((size_t)ar*Le + t)*Vc + k);
        else if (k < 640) a[ks] = ld16a(vpv  + ar*Hd + (k-128));
        else              a[ks] = ld16a(hold + ar*Hd + (k-640));
      }
      f4 acc0 = {0.f,0.f,0.f,0.f}, acc1 = {0.f,0.f,0.f,0.f};
      #pragma unroll
      for (int ks = 0; ks < 18; ks++){
        int k = k2*576 + ks*32 + kl;
        acc0 = MM(a[ks], ldsB(sm, KD, (n2*2+0)*16 + (l&15), k), acc0);
        acc1 = MM(a[ks], ldsB(sm, KD, (n2*2+1)*16 + (l&15), k), acc1);
      }
      float* exch = (float*)(sm + SM_U);
      #pragma unroll
      for (int r = 0; r < 4; r++){
        int row = ((l>>4)<<2) + r;
        exch[((k2*4 + n2*2+0)*16 + row)*16 + (l&15)] = acc0[r];
        exch[((k2*4 + n2*2+1)*16 + row)*16 + (l&15)] = acc1[r];
      }
      __syncthreads();
      {
        int row = tid >> 4, u = tid & 15;
        int gb = cg*16 + u;
        float gi = exch[((0)*16+row)*16+u] + exch[((4)*16+row)*16+u] + bd[0*512+gb];
        float gf = exch[((1)*16+row)*16+u] + exch[((5)*16+row)*16+u] + bd[1*512+gb];
        float gg = exch[((2)*16+row)*16+u] + exch[((6)*16+row)*16+u] + bd[2*512+gb];
        float go = exch[((3)*16+row)*16+u] + exch[((7)*16+row)*16+u] + bd[3*512+gb];
        float fi = sigm(gi), ff = sigm(gf), fg = tanhf(gg), fo = sigm(go);
        cst = ff*cst + fi*fg;
        float hn = fo * tanhf(cst);
        u32 hb = f2bf(hn);
        u32 nb = __shfl_xor((int)hb, 1, 64);
        if ((tid & 1) == 0)
          st32a(hnew + (rg*16+row)*Hd + gb, hb | (nb << 16));
      }
    }
    RGB();

    // ---- S2: q = h_new @ attW^T (4 waves split K, LDS reduce) ----
    {
      f4 acc = {0.f,0.f,0.f,0.f};
      s8 ha[4];
      #pragma unroll
      for (int j = 0; j < 4; j++){
        int k = (wv*4 + j)*32 + kl;
        ha[j] = ld16a(hnew + (rg*16 + (l&15))*Hd + k);
      }
      #pragma unroll
      for (int j = 0; j < 4; j++){
        int k = (wv*4 + j)*32 + kl;
        s8 bb = *(const s8*)(attw + (size_t)(cg*16 + (l&15))*Hd + k);
        acc = MM(ha[j], bb, acc);
      }
      float* exch4 = (float*)(sm + SM_U);
      #pragma unroll
      for (int r = 0; r < 4; r++){
        int row = ((l>>4)<<2) + r;
        exch4[wv*256 + row*16 + (l&15)] = acc[r];
      }
      __syncthreads();
      {
        int row = tid >> 4, col = tid & 15;
        float q = exch4[row*16+col] + exch4[256+row*16+col]
                + exch4[512+row*16+col] + exch4[768+row*16+col];
        st32af(qg + (rg*16+row)*Hd + cg*16 + col, q);
      }
    }
    RGB();

    // ---- S3: flash attention partials (2 WGs per row) ----
    {
      const int row = rg*16 + (cg >> 1), half = cg & 1;
      const int cn = (int)cntp[row], c2 = cn >> 1;
      const int st = half ? c2 : 0, en = half ? cn : c2, n = en - st;
      float* qld = (float*)(sm + SM_U);            // permuted q row
      float* scl = (float*)(sm + SM_U + 2048);     // scores -> weights
      float* red = (float*)(sm + SM_U + 3072);
      { // coalesced bypass load of q, permuted write to LDS
        union { u64 q; float f[2]; } u;
        u.q = ld64a(qg + row*Hd + 2*tid);
        int c0 = 2*tid, c1 = 2*tid+1;
        qld[(c0&15)*32 + (c0>>4)] = u.f[0];
        qld[(c1&15)*32 + (c1>>4)] = u.f[1];
      }
      __syncthreads();
      const int sub = tid >> 5, ln = tid & 31;
      for (int i = sub; i < n; i += 8){
        const u16* e = encc + ((size_t)row*Lc + st + i)*Hd + ln*16;
        s8 ev0 = *(const s8*)(e);
        s8 ev1 = *(const s8*)(e + 8);
        float s = 0.f;
        #pragma unroll
        for (int j = 0; j < 8; j++) s += bf2f((u16)ev0[j]) * qld[j*32 + ln];
        #pragma unroll
        for (int j = 0; j < 8; j++) s += bf2f((u16)ev1[j]) * qld[(j+8)*32 + ln];
        #pragma unroll
        for (int m = 1; m < 32; m <<= 1) s += __shfl_xor(s, m, 64);
        if (ln == 0) scl[i] = s;
      }
      __syncthreads();
      float mloc = -1e30f;
      for (int i = tid; i < n; i += NT) mloc = fmaxf(mloc, scl[i]);
      mloc = wredmax(mloc);
      if ((tid&63) == 0) red[tid>>6] = mloc;
      __syncthreads();
      float M = fmaxf(fmaxf(red[0],red[1]), fmaxf(red[2],red[3]));
      __syncthreads();
      float sloc = 0.f;
      for (int i = tid; i < n; i += NT){ float w = expf(scl[i]-M); scl[i] = w; sloc += w; }
      sloc = wredsum(sloc);
      if ((tid&63) == 0) red[tid>>6] = sloc;
      __syncthreads();
      float S = red[0]+red[1]+red[2]+red[3];
      float a0 = 0.f, a1 = 0.f;
      const int h0 = tid*2;
      const u16* eb = encc + ((size_t)row*Lc + st)*Hd + h0;
      for (int i = 0; i < n; i++){
        float w = scl[i];
        u32 ev = *(const u32*)(eb + (size_t)i*Hd);
        a0 += w * bf2f((u16)(ev & 0xffffu));
        a1 += w * bf2f((u16)(ev >> 16));
      }
      union { u64 q; float f[2]; } pk; pk.f[0] = a0; pk.f[1] = a1;
      st64a(pacc + (size_t)lid*Hd + h0, pk.q);
      if (tid == 0){ st32af(pm + lid, M); st32af(ps + lid, S); }
    }
    RGB();

    // ---- S4: combine + Vnew + logits + CE (rowgroup leader cg==0) ----
    if (cg == 0){
      const int b0 = rg*16;
      float* sc4 = (float*)(sm + SM_U + 3072);
      if (tid < 16){
        int l1 = rg*32 + 2*tid;
        float m1 = ld32a(pm+l1), m2 = ld32a(pm+l1+1);
        float s1 = ld32a(ps+l1), s2 = ld32a(ps+l1+1);
        float M = fmaxf(m1, m2);
        float e1 = expf(m1-M), e2 = expf(m2-M);
        float den = s1*e1 + s2*e2;
        sc4[tid*2]   = e1/den;
        sc4[tid*2+1] = e2/den;
      }
      __syncthreads();
      for (int idx = tid; idx < 16*512; idx += NT){
        int row = idx >> 9, h = idx & 511, b = b0 + row;
        int l1 = rg*32 + 2*row;
        float v = ld32a(pacc + (size_t)l1*Hd + h)*sc4[row*2]
                + ld32a(pacc + (size_t)(l1+1)*Hd + h)*sc4[row*2+1];
        attnb[b*Hd + h] = f2bf(v);   // leader-local: normal cached store
      }
      __syncthreads();
      // Vnew = [h, attn] @ outW^T + out_b
      f4 vac[8];
      #pragma unroll
      for (int nn = 0; nn < 8; nn++){
        float ob = p.outb[(wv*8+nn)*16 + (l&15)];
        f4 z = {ob,ob,ob,ob}; vac[nn] = z;
      }
      s8 hfr[16];
      #pragma unroll
      for (int ks = 0; ks < 16; ks++)
        hfr[ks] = ld16a(hnew + (b0+(l&15))*Hd + ks*32 + kl);
      for (int ks = 0; ks < 32; ks++){
        s8 a = (ks < 16) ? hfr[ks]
                         : *(const s8*)(attnb + (b0+(l&15))*Hd + (ks-16)*32 + kl);
        #pragma unroll
        for (int nn = 0; nn < 8; nn++){
          int ncol = (wv*8+nn)*16 + (l&15);
          s8 bb = *(const s8*)(outw + (size_t)ncol*1024 + ks*32 + kl);
          vac[nn] = MM(a, bb, vac[nn]);
        }
      }
      #pragma unroll
      for (int nn = 0; nn < 8; nn++){
        #pragma unroll
        for (int r = 0; r < 4; r++){
          int ncol = (wv*8+nn)*16 + (l&15);
          int b = b0 + ((l>>4)<<2) + r;
          float v = vac[nn][r];
          u32 hb = f2bf(v);
          u32 nb = __shfl_xor((int)hb, 1, 64);
          if ((l & 1) == 0)
            st32a(vpv + b*Hd + ncol, hb | (nb << 16));   // cross-WG: bypass
          tnh[b*Hd + ncol] = f2bf(tanhf(v));             // leader-local
        }
      }
      __syncthreads();
      // logits = tanh(Vnew) @ vocW^T + voc_b
      float* lg = (float*)(sm + SM_U);
      f4 lac[2];
      #pragma unroll
      for (int v2 = 0; v2 < 2; v2++){
        float vb = p.vocb[(wv*2+v2)*16 + (l&15)];
        f4 z = {vb,vb,vb,vb}; lac[v2] = z;
      }
      for (int ks = 0; ks < 16; ks++){
        int k = ks*32 + kl;
        s8 a = *(const s8*)(tnh + (b0+(l&15))*Hd + k);
        #pragma unroll
        for (int v2 = 0; v2 < 2; v2++){
          int vcol = (wv*2+v2)*16 + (l&15);
          s8 bb = *(const s8*)(vocw + (size_t)vcol*Hd + k);
          lac[v2] = MM(a, bb, lac[v2]);
        }
      }
      #pragma unroll
      for (int v2 = 0; v2 < 2; v2++){
        #pragma unroll
        for (int r = 0; r < 4; r++){
          int vcol = (wv*2+v2)*16 + (l&15);
          int row = ((l>>4)<<2) + r;
          lg[row*128 + vcol] = lac[v2][r];
        }
      }
      __syncthreads();
      // CE
      {
        int row = tid >> 4, i = tid & 15;
        int b = b0 + row;
        float lm = -1e30f;
        #pragma unroll
        for (int j = 0; j < 8; j++) lm = fmaxf(lm, lg[row*128 + i*8 + j]);
        #pragma unroll
        for (int m = 1; m < 16; m <<= 1) lm = fmaxf(lm, __shfl_xor(lm, m, 64));
        float le = 0.f;
        #pragma unroll
        for (int j = 0; j < 8; j++) le += expf(lg[row*128 + i*8 + j] - lm);
        #pragma unroll
        for (int m = 1; m < 16; m <<= 1) le += __shfl_xor(le, m, 64);
        if (i == 0){
          int tgt = p.E[b*Le + (t+1)];
          float lt = lg[row*128 + tgt];
          if (tgt != 0){ accN += logf(le) + lm - lt; accC += 1.f; }
        }
      }
    }
    RGB();
  }

  // ================= loss =================
  if (cg == 0 && (tid&15) == 0){
    atomicAdd(losp + 0, accN);
    atomicAdd(losp + 1, accC);
  }
  GBall();
  if (wg == 0 && tid == 0) p.out[0] = losp[0] / fmaxf(losp[1], 1.f);
}

extern "C" void kernel_launch(void* const* d_in, const int* in_sizes, int n_in,
                              void* d_out, int out_size, void* d_ws, size_t ws_size,
                              hipStream_t stream)
{
  hipFuncSetAttribute(reinterpret_cast<const void*>(k_main),
                      hipFuncAttributeMaxDynamicSharedMemorySize, SM_BYTES);
  hipMemsetAsync(d_ws, 0, 2048, stream);   // barrier counters reset every call

  P prm;
  prm.C    = (const float*)d_in[0];
  prm.Cpad = (const int*)  d_in[1];
  prm.E    = (const int*)  d_in[2];
  prm.Eemb = (const float*)d_in[3];
  prm.eWih = (const float*)d_in[4];
  prm.eWhh = (const float*)d_in[5];
  prm.ebih = (const float*)d_in[6];
  prm.ebhh = (const float*)d_in[7];
  prm.dWih = (const float*)d_in[8];
  prm.dWhh = (const float*)d_in[9];
  prm.dbih = (const float*)d_in[10];
  prm.dbhh = (const float*)d_in[11];
  prm.attW = (const float*)d_in[12];
  prm.outW = (const float*)d_in[13];
  prm.outb = (const float*)d_in[14];
  prm.vocW = (const float*)d_in[15];
  prm.vocb = (const float*)d_in[16];
  prm.ws   = (char*)d_ws;
  prm.out  = (float*)d_out;

  k_main<<<dim3(NWG), dim3(NT), SM_BYTES, stream>>>(prm);
}

// Round 4
// 26100.720 us; speedup vs baseline: 3.7017x; 3.7017x over previous
//
#include <hip/hip_runtime.h>
#include <hip/hip_bf16.h>

// Persistent-kernel seq2seq (enc LSTM -> attn decoder -> CE loss) for MI355X.
// 256 WGs x 256 thr, 1 WG/CU (160KB LDS).
// R4: decoder restructured to 4 balanced all-CU phases/step with wide,
// independent (pipelineable) loads everywhere. Softmax combine folded into
// the Vnew MFMA via pre-scaled partial-A fragments; logits+CE piggyback on
// the Vnew phase with a 1-step lag. Flag-based fence-free barriers.

#define NWG 256
#define NT  256

typedef unsigned short u16;
typedef unsigned int   u32;
typedef unsigned long long u64;
typedef __attribute__((ext_vector_type(4))) float f4;
typedef __attribute__((ext_vector_type(8))) short s8;

constexpr int Bv = 128, Lc = 512, Le = 512, Hd = 512, Vc = 128;
constexpr int KE = 640;   // enc gate GEMM K = V + H
constexpr int KD = 1152;  // dec gate GEMM K = V + H + H

// ---- workspace layout (bytes) ----
// [0,4096): barrier counters/flags.
constexpr size_t O_WENC = 4096;                                  // bf16 [2048][640]
constexpr size_t O_WDEC = O_WENC + (size_t)2048*KE*2;            // bf16 [2048][1152]
constexpr size_t O_ATTW = O_WDEC + (size_t)2048*KD*2;            // bf16 [512][512]
constexpr size_t O_OUTW = O_ATTW + (size_t)512*512*2;            // bf16 [512][1024]
constexpr size_t O_VOCW = O_OUTW + (size_t)512*1024*2;           // bf16 [128][512]
constexpr size_t O_BE   = O_VOCW + (size_t)128*512*2;            // f32 [2048]
constexpr size_t O_BD   = O_BE + 8192;                           // f32 [2048]
constexpr size_t O_H    = O_BD + 8192;                           // bf16 [2][128][512]
constexpr size_t O_VPRV = O_H + (size_t)2*128*512*2;             // bf16 [128][512]
constexpr size_t O_Q    = O_VPRV + (size_t)128*512*2;            // f32 [128][512]
constexpr size_t O_TNH  = O_Q + (size_t)128*512*4;               // bf16 [2][128][512]
constexpr size_t O_PFX  = O_TNH + (size_t)2*128*512*2;           // u32 [128][512]
constexpr size_t O_CNT  = O_PFX + (size_t)128*512*4;             // u32 [128]
constexpr size_t O_PMS  = O_CNT + 512;                           // u64 [256] (m,s)
constexpr size_t O_PACC = O_PMS + 2048;                          // bf16 [256][512]
constexpr size_t O_LOSS = O_PACC + (size_t)256*512*2;            // f32 [2]
constexpr size_t O_ENC  = O_LOSS + 256;                          // bf16 [128][512][512]

// ---- LDS ----
constexpr int SM_U     = 64*KD*2;          // 147456: weight slice end
constexpr int SM_BYTES = SM_U + 16384;     // = 163840 (160KB)

struct P {
  const float *C; const int *Cpad; const int *E; const float *Eemb;
  const float *eWih,*eWhh,*ebih,*ebhh;
  const float *dWih,*dWhh,*dbih,*dbhh;
  const float *attW,*outW,*outb,*vocW,*vocb;
  char* ws; float* out;
};

__device__ inline u16 f2bf(float x){
  u32 u = __float_as_uint(x);
  return (u16)((u + 0x7fffu + ((u>>16)&1u)) >> 16);
}
__device__ inline float bf2f(u16 b){ return __uint_as_float(((u32)b)<<16); }
__device__ inline float sigm(float x){ return 1.f/(1.f+expf(-x)); }

__device__ inline f4 MM(s8 a, s8 b, f4 c){
  return __builtin_amdgcn_mfma_f32_16x16x32_bf16(a, b, c, 0, 0, 0);
}

// device-scope relaxed (cache-bypass) access helpers
__device__ inline u64 ld64a(const void* p){
  return __hip_atomic_load((const u64*)p, __ATOMIC_RELAXED, __HIP_MEMORY_SCOPE_AGENT);
}
__device__ inline u32 ld32u(const void* p){
  return __hip_atomic_load((const u32*)p, __ATOMIC_RELAXED, __HIP_MEMORY_SCOPE_AGENT);
}
__device__ inline void st64a(void* p, u64 v){
  __hip_atomic_store((u64*)p, v, __ATOMIC_RELAXED, __HIP_MEMORY_SCOPE_AGENT);
}
__device__ inline void st32a(void* p, u32 v){
  __hip_atomic_store((u32*)p, v, __ATOMIC_RELAXED, __HIP_MEMORY_SCOPE_AGENT);
}
__device__ inline s8 ld16a(const void* p){
  union { u64 q[2]; s8 v; } u;
  u.q[0] = ld64a(p);
  u.q[1] = ld64a((const char*)p + 8);
  return u.v;
}

__device__ inline s8 cvt8(const float* p){
  f4 u = *(const f4*)p, v = *(const f4*)(p+4);
  s8 r;
  r[0]=(short)f2bf(u[0]); r[1]=(short)f2bf(u[1]); r[2]=(short)f2bf(u[2]); r[3]=(short)f2bf(u[3]);
  r[4]=(short)f2bf(v[0]); r[5]=(short)f2bf(v[1]); r[6]=(short)f2bf(v[2]); r[7]=(short)f2bf(v[3]);
  return r;
}

__device__ inline s8 ldsB(const char* sm, int K, int srow, int k){
  int byte = srow*(K*2) + k*2;
  byte ^= (srow&7)<<4;
  return *(const s8*)(sm + byte);
}

__device__ inline float wredmax(float v){
  #pragma unroll
  for (int m=32;m;m>>=1) v = fmaxf(v, __shfl_xor(v,m,64));
  return v;
}
__device__ inline float wredsum(float v){
  #pragma unroll
  for (int m=32;m;m>>=1) v += __shfl_xor(v,m,64);
  return v;
}

extern "C" __global__ void __launch_bounds__(NT,1) k_main(P p)
{
  extern __shared__ char sm[];
  const int wg = blockIdx.x, tid = threadIdx.x;
  const int gt = wg*NT + tid;
  const int rg = wg & 7, cg = wg >> 3;     // rowgroup likely = one XCD
  const int lid = rg*32 + cg;

  char* ws = p.ws;
  u32*  barAll  = (u32*)ws;
  u32*  flagAll = (u32*)(ws + 128);
  u32*  barRG   = (u32*)(ws + 512 + rg*256);
  u32*  flagRG  = (u32*)(ws + 512 + rg*256 + 128);
  u16*  wenc = (u16*)(ws + O_WENC);
  u16*  wdec = (u16*)(ws + O_WDEC);
  u16*  attw = (u16*)(ws + O_ATTW);
  u16*  outw = (u16*)(ws + O_OUTW);
  u16*  vocw = (u16*)(ws + O_VOCW);
  float* be  = (float*)(ws + O_BE);
  float* bd  = (float*)(ws + O_BD);
  u16*  hbf  = (u16*)(ws + O_H);
  u16*  vpv  = (u16*)(ws + O_VPRV);
  float* qg  = (float*)(ws + O_Q);
  u16*  tnhb = (u16*)(ws + O_TNH);
  u32*  pfx  = (u32*)(ws + O_PFX);
  u32*  cntp = (u32*)(ws + O_CNT);
  u64*  pms  = (u64*)(ws + O_PMS);
  u16*  pacc16 = (u16*)(ws + O_PACC);
  float* losp= (float*)(ws + O_LOSS);
  u16*  encc = (u16*)(ws + O_ENC);

  u32 genA = 0, genG = 0;

  auto GBall = [&](){
    genA++;
    __syncthreads();
    if (tid == 0){
      __builtin_amdgcn_fence(__ATOMIC_RELEASE, "agent");
      u32 old = __hip_atomic_fetch_add(barAll, 1u, __ATOMIC_RELAXED, __HIP_MEMORY_SCOPE_AGENT);
      if (old == genA*(u32)NWG - 1u) st32a(flagAll, genA);
      else while (ld32u(flagAll) < genA) __builtin_amdgcn_s_sleep(2);
      __builtin_amdgcn_fence(__ATOMIC_ACQUIRE, "agent");
    }
    __syncthreads();
  };
  auto RGB = [&](){
    genG++;
    __syncthreads();
    if (tid == 0){
      u32 old = __hip_atomic_fetch_add(barRG, 1u, __ATOMIC_RELAXED, __HIP_MEMORY_SCOPE_AGENT);
      if (old == genG*32u - 1u) st32a(flagRG, genG);
      else while (ld32u(flagRG) < genG) __builtin_amdgcn_s_sleep(2);
      __builtin_amdgcn_fence(__ATOMIC_ACQUIRE, "workgroup");
    }
    __syncthreads();
  };

  // ================= phase 0 =================
  for (int i = gt; i < 2048*KE; i += NWG*NT){
    int row = i / KE, k = i - row*KE;
    float v = (k < 128) ? p.eWih[row*128 + k] : p.eWhh[row*512 + (k-128)];
    wenc[i] = f2bf(v);
  }
  for (int i = gt; i < 2048*KD; i += NWG*NT){
    int row = i / KD, k = i - row*KD;
    float v = (k < 640) ? p.dWih[row*640 + k] : p.dWhh[row*512 + (k-640)];
    wdec[i] = f2bf(v);
  }
  for (int i = gt; i < 512*512;  i += NWG*NT) attw[i] = f2bf(p.attW[i]);
  for (int i = gt; i < 512*1024; i += NWG*NT) outw[i] = f2bf(p.outW[i]);
  for (int i = gt; i < 128*512;  i += NWG*NT) vocw[i] = f2bf(p.vocW[i]);
  for (int i = gt; i < 2048;     i += NWG*NT){ be[i] = p.ebih[i]+p.ebhh[i]; bd[i] = p.dbih[i]+p.dbhh[i]; }
  { u32* hz = (u32*)hbf; for (int i = gt; i < 65536; i += NWG*NT) hz[i] = 0; }
  { u32* vz = (u32*)vpv; for (int i = gt; i < 32768; i += NWG*NT) vz[i] = 0; }
  if (gt == 0){ losp[0] = 0.f; losp[1] = 0.f; }
  if (wg < 128){
    int* padl = (int*)(sm + SM_U);
    for (int i = tid; i < 512; i += NT) padl[i] = p.Cpad[wg*512 + i];
    __syncthreads();
    if (tid == 0){
      u32 run = 0;
      for (int tt = 0; tt < 512; tt++){ pfx[wg*512+tt] = run; if (padl[tt] == 0) run++; }
      cntp[wg] = run;
    }
    __syncthreads();
  }
  GBall();

  const int l  = tid & 63, wv = tid >> 6;
  const int n2 = wv >> 1, k2 = wv & 1;
  const int kl = (l>>4) << 3;
  const int ar = rg*16 + (l&15);
  float cst = 0.f;
  float accN = 0.f, accC = 0.f;

  // logits + CE for step tl (leader WG of rowgroup only)
  auto S6 = [&](int tl){
    const u16* tb = tnhb + (size_t)(tl&1)*Bv*Hd;
    float* lg = (float*)(sm + SM_U + 8192);
    s8 ta[16];
    #pragma unroll
    for (int ks = 0; ks < 16; ks++)
      ta[ks] = ld16a(tb + (size_t)(rg*16+(l&15))*Hd + ks*32 + kl);
    f4 lac0 = {0,0,0,0}, lac1 = {0,0,0,0};
    const int c0 = (wv*2)*16 + (l&15), c1 = (wv*2+1)*16 + (l&15);
    #pragma unroll
    for (int ks = 0; ks < 16; ks++){
      int k = ks*32 + kl;
      lac0 = MM(ta[ks], *(const s8*)(vocw + (size_t)c0*Hd + k), lac0);
      lac1 = MM(ta[ks], *(const s8*)(vocw + (size_t)c1*Hd + k), lac1);
    }
    #pragma unroll
    for (int r = 0; r < 4; r++){
      int row = ((l>>4)<<2) + r;
      lg[row*128 + c0] = lac0[r] + p.vocb[c0];
      lg[row*128 + c1] = lac1[r] + p.vocb[c1];
    }
    __syncthreads();
    {
      int rowi = tid>>4, ii = tid&15, b = rg*16 + rowi;
      float lm = -1e30f;
      #pragma unroll
      for (int j=0;j<8;j++) lm = fmaxf(lm, lg[rowi*128 + ii*8 + j]);
      #pragma unroll
      for (int m=1;m<16;m<<=1) lm = fmaxf(lm, __shfl_xor(lm,m,64));
      float le = 0.f;
      #pragma unroll
      for (int j=0;j<8;j++) le += expf(lg[rowi*128 + ii*8 + j] - lm);
      #pragma unroll
      for (int m=1;m<16;m<<=1) le += __shfl_xor(le,m,64);
      if (ii == 0){
        int tgt = p.E[b*Le + tl + 1];
        if (tgt != 0){ accN += logf(le) + lm - lg[rowi*128 + tgt]; accC += 1.f; }
      }
    }
    __syncthreads();
  };

  // ================= encoder =================
  {
    const int chunks = KE/8;
    for (int idx = tid; idx < 64*chunks; idx += NT){
      int s = idx / chunks, cc = idx - s*chunks;
      int grow = (s>>4)*512 + cg*16 + (s&15);
      uint4 v = *(const uint4*)(wenc + (size_t)grow*KE + cc*8);
      int byte = s*(KE*2) + cc*16; byte ^= (s&7)<<4;
      *(uint4*)(sm + byte) = v;
    }
  }
  __syncthreads();

  for (int t = 0; t < Lc; t++){
    const u16* hold = hbf + (t&1)*Bv*Hd;
    u16* hnew       = hbf + ((t+1)&1)*Bv*Hd;
    s8 a[10];
    #pragma unroll
    for (int ks = 0; ks < 10; ks++){
      int k = k2*320 + ks*32 + kl;
      if (k < 128) a[ks] = cvt8(p.C + ((size_t)ar*Lc + t)*Vc + k);
      else         a[ks] = ld16a(hold + (size_t)ar*Hd + (k-128));
    }
    f4 acc0 = {0,0,0,0}, acc1 = {0,0,0,0};
    #pragma unroll
    for (int ks = 0; ks < 10; ks++){
      int k = k2*320 + ks*32 + kl;
      acc0 = MM(a[ks], ldsB(sm, KE, (n2*2+0)*16 + (l&15), k), acc0);
      acc1 = MM(a[ks], ldsB(sm, KE, (n2*2+1)*16 + (l&15), k), acc1);
    }
    float* exch = (float*)(sm + SM_U);
    #pragma unroll
    for (int r = 0; r < 4; r++){
      int row = ((l>>4)<<2) + r;
      exch[((k2*4 + n2*2+0)*16 + row)*16 + (l&15)] = acc0[r];
      exch[((k2*4 + n2*2+1)*16 + row)*16 + (l&15)] = acc1[r];
    }
    __syncthreads();
    {
      int row = tid >> 4, u = tid & 15;
      int gb = cg*16 + u;
      float gi = exch[((0)*16+row)*16+u] + exch[((4)*16+row)*16+u] + be[0*512+gb];
      float gf = exch[((1)*16+row)*16+u] + exch[((5)*16+row)*16+u] + be[1*512+gb];
      float gg = exch[((2)*16+row)*16+u] + exch[((6)*16+row)*16+u] + be[2*512+gb];
      float go = exch[((3)*16+row)*16+u] + exch[((7)*16+row)*16+u] + be[3*512+gb];
      float fi = sigm(gi), ff = sigm(gf), fg = tanhf(gg), fo = sigm(go);
      cst = ff*cst + fi*fg;
      float hn = fo * tanhf(cst);
      int b = rg*16 + row;
      u32 hb = f2bf(hn);
      u32 nb = __shfl_xor((int)hb, 1, 64);
      if ((tid & 1) == 0){
        u32 pk = hb | (nb << 16);
        st32a(hnew + (size_t)b*Hd + gb, pk);
        if (p.Cpad[b*Lc + t] == 0){
          u32 pos = pfx[b*Lc + t];
          st32a(encc + ((size_t)b*Lc + pos)*Hd + gb, pk);
        }
      }
    }
    RGB();
  }

  GBall();   // flush+invalidate once: decoder reads encc/pfx CACHED safely

  // ================= decoder =================
  {
    const int chunks = KD/8;
    for (int idx = tid; idx < 64*chunks; idx += NT){
      int s = idx / chunks, cc = idx - s*chunks;
      int grow = (s>>4)*512 + cg*16 + (s&15);
      uint4 v = *(const uint4*)(wdec + (size_t)grow*KD + cc*8);
      int byte = s*(KD*2) + cc*16; byte ^= (s&7)<<4;
      *(uint4*)(sm + byte) = v;
    }
  }
  __syncthreads();

  for (int t = 0; t < Le-1; t++){
    const u16* hold = hbf + (t&1)*Bv*Hd;
    u16* hnew       = hbf + ((t+1)&1)*Bv*Hd;

    // ---- S1: gates GEMM + cell ----
    {
      s8 a[18];
      #pragma unroll
      for (int ks = 0; ks < 18; ks++){
        int k = k2*576 + ks*32 + kl;
        if (k < 128)      a[ks] = cvt8(p.Eemb + ((size_t)ar*Le + t)*Vc + k);
        else if (k < 640) a[ks] = ld16a(vpv  + (size_t)ar*Hd + (k-128));
        else              a[ks] = ld16a(hold + (size_t)ar*Hd + (k-640));
      }
      f4 acc0 = {0,0,0,0}, acc1 = {0,0,0,0};
      #pragma unroll
      for (int ks = 0; ks < 18; ks++){
        int k = k2*576 + ks*32 + kl;
        acc0 = MM(a[ks], ldsB(sm, KD, (n2*2+0)*16 + (l&15), k), acc0);
        acc1 = MM(a[ks], ldsB(sm, KD, (n2*2+1)*16 + (l&15), k), acc1);
      }
      float* exch = (float*)(sm + SM_U);
      #pragma unroll
      for (int r = 0; r < 4; r++){
        int row = ((l>>4)<<2) + r;
        exch[((k2*4 + n2*2+0)*16 + row)*16 + (l&15)] = acc0[r];
        exch[((k2*4 + n2*2+1)*16 + row)*16 + (l&15)] = acc1[r];
      }
      __syncthreads();
      {
        int row = tid >> 4, u = tid & 15;
        int gb = cg*16 + u;
        float gi = exch[((0)*16+row)*16+u] + exch[((4)*16+row)*16+u] + bd[0*512+gb];
        float gf = exch[((1)*16+row)*16+u] + exch[((5)*16+row)*16+u] + bd[1*512+gb];
        float gg = exch[((2)*16+row)*16+u] + exch[((6)*16+row)*16+u] + bd[2*512+gb];
        float go = exch[((3)*16+row)*16+u] + exch[((7)*16+row)*16+u] + bd[3*512+gb];
        float fi = sigm(gi), ff = sigm(gf), fg = tanhf(gg), fo = sigm(go);
        cst = ff*cst + fi*fg;
        float hn = fo * tanhf(cst);
        u32 hb = f2bf(hn);
        u32 nb = __shfl_xor((int)hb, 1, 64);
        if ((tid & 1) == 0)
          st32a(hnew + (size_t)(rg*16+row)*Hd + gb, hb | (nb << 16));
      }
    }
    RGB();

    // ---- S2: q = h_new @ attW^T (K split across 4 waves) ----
    {
      s8 ha[4];
      #pragma unroll
      for (int j = 0; j < 4; j++){
        int k = (wv*4 + j)*32 + kl;
        ha[j] = ld16a(hnew + (size_t)(rg*16 + (l&15))*Hd + k);
      }
      f4 acc = {0,0,0,0};
      #pragma unroll
      for (int j = 0; j < 4; j++){
        int k = (wv*4 + j)*32 + kl;
        acc = MM(ha[j], *(const s8*)(attw + (size_t)(cg*16 + (l&15))*Hd + k), acc);
      }
      float* exch4 = (float*)(sm + SM_U);
      #pragma unroll
      for (int r = 0; r < 4; r++)
        exch4[wv*256 + (((l>>4)<<2)+r)*16 + (l&15)] = acc[r];
      __syncthreads();
      {
        int row = tid >> 4, col = tid & 15;
        float q = exch4[row*16+col] + exch4[256+row*16+col]
                + exch4[512+row*16+col] + exch4[768+row*16+col];
        float qn = __shfl_xor(q, 1, 64);
        if ((tid & 1) == 0){
          union { u64 u; float f[2]; } pk; pk.f[0]=q; pk.f[1]=qn;
          st64a(qg + (size_t)(rg*16+row)*Hd + cg*16 + col, pk.u);
        }
      }
    }
    RGB();

    // ---- S3: attention partials (2 WGs per row) ----
    {
      const int row = rg*16 + (cg >> 1), hf = cg & 1;
      const int cn = (int)cntp[row], c2 = cn >> 1;
      const int st = hf ? c2 : 0, en = hf ? cn : c2, n = en - st;
      float* qld = (float*)(sm + SM_U);
      float* scl = (float*)(sm + SM_U + 2048);
      float* red = (float*)(sm + SM_U + 3104);
      float* part= (float*)(sm + SM_U + 8192);
      {
        union { u64 q; float f[2]; } u;
        u.q = ld64a(qg + (size_t)row*Hd + 2*tid);
        int c0 = 2*tid, c1 = c0+1;
        qld[(c0&15)*32 + (c0>>4)] = u.f[0];
        qld[(c1&15)*32 + (c1>>4)] = u.f[1];
      }
      __syncthreads();
      const int pg8 = tid >> 5, hg32 = tid & 31;
      const u16* ebase = encc + ((size_t)row*Lc + st)*Hd;
      for (int i = pg8; i < n; i += 8){
        const u16* e = ebase + (size_t)i*Hd + hg32*16;
        s8 ev0 = *(const s8*)(e);
        s8 ev1 = *(const s8*)(e+8);
        float s = 0.f;
        #pragma unroll
        for (int j=0;j<8;j++) s += bf2f((u16)ev0[j]) * qld[j*32+hg32];
        #pragma unroll
        for (int j=0;j<8;j++) s += bf2f((u16)ev1[j]) * qld[(j+8)*32+hg32];
        #pragma unroll
        for (int m=1;m<32;m<<=1) s += __shfl_xor(s, m, 64);
        if (hg32 == 0) scl[i] = s;
      }
      __syncthreads();
      float mloc = -1e30f;
      for (int i = tid; i < n; i += NT) mloc = fmaxf(mloc, scl[i]);
      mloc = wredmax(mloc);
      if ((tid&63)==0) red[tid>>6] = mloc;
      __syncthreads();
      float M = fmaxf(fmaxf(red[0],red[1]), fmaxf(red[2],red[3]));
      __syncthreads();
      float sloc = 0.f;
      for (int i = tid; i < n; i += NT){ float w = expf(scl[i]-M); scl[i]=w; sloc += w; }
      sloc = wredsum(sloc);
      if ((tid&63)==0) red[tid>>6] = sloc;
      __syncthreads();
      float S = red[0]+red[1]+red[2]+red[3];
      // weighted accumulation: thread (wave, hg64) -> 8 h, 4-deep ILP
      const int hg64 = tid & 63;
      float a8[8] = {0,0,0,0,0,0,0,0};
      const u16* eb2 = ebase + hg64*8;
      int i = wv;
      for (; i + 12 < n; i += 16){
        s8 e0 = *(const s8*)(eb2 + (size_t)i*Hd);
        s8 e1 = *(const s8*)(eb2 + (size_t)(i+4)*Hd);
        s8 e2 = *(const s8*)(eb2 + (size_t)(i+8)*Hd);
        s8 e3 = *(const s8*)(eb2 + (size_t)(i+12)*Hd);
        float w0=scl[i], w1=scl[i+4], w2=scl[i+8], w3=scl[i+12];
        #pragma unroll
        for (int j=0;j<8;j++) a8[j] += w0*bf2f((u16)e0[j]);
        #pragma unroll
        for (int j=0;j<8;j++) a8[j] += w1*bf2f((u16)e1[j]);
        #pragma unroll
        for (int j=0;j<8;j++) a8[j] += w2*bf2f((u16)e2[j]);
        #pragma unroll
        for (int j=0;j<8;j++) a8[j] += w3*bf2f((u16)e3[j]);
      }
      for (; i < n; i += 4){
        s8 e0 = *(const s8*)(eb2 + (size_t)i*Hd);
        float w0 = scl[i];
        #pragma unroll
        for (int j=0;j<8;j++) a8[j] += w0*bf2f((u16)e0[j]);
      }
      { f4 v0 = {a8[0],a8[1],a8[2],a8[3]}, v1 = {a8[4],a8[5],a8[6],a8[7]};
        *(f4*)(part + wv*512 + hg64*8)     = v0;
        *(f4*)(part + wv*512 + hg64*8 + 4) = v1; }
      __syncthreads();
      {
        int h0 = tid*2;
        float s0 = 0.f, s1 = 0.f;
        #pragma unroll
        for (int pg = 0; pg < 4; pg++){
          float2 pr = *(float2*)(part + pg*512 + h0);
          s0 += pr.x; s1 += pr.y;
        }
        u32 pk = (u32)f2bf(s0) | ((u32)f2bf(s1) << 16);
        st32a(pacc16 + (size_t)lid*Hd + h0, pk);
      }
      if (tid == 0){
        union { u64 q; float f[2]; } pk; pk.f[0]=M; pk.f[1]=S;
        st64a(pms + lid, pk.q);
      }
    }
    RGB();

    // ---- S5: Vnew (softmax-combine folded) + prev-step logits/CE ----
    {
      float* sc2 = (float*)(sm + SM_U);
      float* vex = (float*)(sm + SM_U + 4096);
      if (tid < 16){
        union { u64 q; float f[2]; } uA, uB;
        uA.q = ld64a(pms + rg*32 + 2*tid);
        uB.q = ld64a(pms + rg*32 + 2*tid + 1);
        float M = fmaxf(uA.f[0], uB.f[0]);
        float eA = expf(uA.f[0]-M), eB = expf(uB.f[0]-M);
        float den = uA.f[1]*eA + uB.f[1]*eB;
        sc2[2*tid]   = eA/den;
        sc2[2*tid+1] = eB/den;
      }
      __syncthreads();
      if (cg == 0 && t > 0) S6(t-1);
      // 48 K-steps (16 h + 16 pA + 16 pB) split 12 per wave
      const int colc = cg*16 + (l&15);
      const u16* pb0 = pacc16 + ((size_t)(rg*32 + (l&15)*2))*Hd;
      float scA = sc2[(l&15)*2], scB = sc2[(l&15)*2+1];
      s8 raw[12];
      #pragma unroll
      for (int ks = 0; ks < 12; ks++){
        int km = wv*12 + ks;
        const void* ap;
        if (km < 16)      ap = hnew + (size_t)(rg*16+(l&15))*Hd + km*32 + kl;
        else if (km < 32) ap = pb0 + (km-16)*32 + kl;
        else              ap = pb0 + Hd + (km-32)*32 + kl;
        raw[ks] = ld16a(ap);
      }
      f4 vac = {0,0,0,0};
      #pragma unroll
      for (int ks = 0; ks < 12; ks++){
        int km = wv*12 + ks;
        s8 af;
        if (km < 16) af = raw[ks];
        else {
          float sc = (km < 32) ? scA : scB;
          #pragma unroll
          for (int j = 0; j < 8; j++) af[j] = (short)f2bf(bf2f((u16)raw[ks][j]) * sc);
        }
        int k = (km < 16) ? km*32+kl : ((km < 32) ? 512 + (km-16)*32+kl : 512 + (km-32)*32+kl);
        vac = MM(af, *(const s8*)(outw + (size_t)colc*1024 + k), vac);
      }
      #pragma unroll
      for (int r = 0; r < 4; r++)
        vex[wv*256 + (((l>>4)<<2)+r)*16 + (l&15)] = vac[r];
      __syncthreads();
      {
        int row = tid >> 4, col = tid & 15;
        float v = vex[row*16+col] + vex[256+row*16+col]
                + vex[512+row*16+col] + vex[768+row*16+col] + p.outb[cg*16+col];
        u32 vb = f2bf(v), tb2 = f2bf(tanhf(v));
        u32 vn = __shfl_xor((int)vb, 1, 64);
        u32 tn2 = __shfl_xor((int)tb2, 1, 64);
        if ((tid & 1) == 0){
          int b = rg*16 + row;
          u16* tnw = tnhb + (size_t)(t&1)*Bv*Hd;
          st32a(vpv + (size_t)b*Hd + cg*16 + col, vb | (vn<<16));
          st32a(tnw + (size_t)b*Hd + cg*16 + col, tb2 | (tn2<<16));
        }
      }
    }
    RGB();
  }

  // final lagged logits/CE for t = Le-2
  if (cg == 0) S6(Le-2);

  // ================= loss =================
  if (cg == 0 && (tid&15) == 0){
    atomicAdd(losp + 0, accN);
    atomicAdd(losp + 1, accC);
  }
  GBall();
  if (wg == 0 && tid == 0) p.out[0] = losp[0] / fmaxf(losp[1], 1.f);
}

extern "C" void kernel_launch(void* const* d_in, const int* in_sizes, int n_in,
                              void* d_out, int out_size, void* d_ws, size_t ws_size,
                              hipStream_t stream)
{
  hipFuncSetAttribute(reinterpret_cast<const void*>(k_main),
                      hipFuncAttributeMaxDynamicSharedMemorySize, SM_BYTES);
  hipMemsetAsync(d_ws, 0, 4096, stream);   // barrier counters/flags reset

  P prm;
  prm.C    = (const float*)d_in[0];
  prm.Cpad = (const int*)  d_in[1];
  prm.E    = (const int*)  d_in[2];
  prm.Eemb = (const float*)d_in[3];
  prm.eWih = (const float*)d_in[4];
  prm.eWhh = (const float*)d_in[5];
  prm.ebih = (const float*)d_in[6];
  prm.ebhh = (const float*)d_in[7];
  prm.dWih = (const float*)d_in[8];
  prm.dWhh = (const float*)d_in[9];
  prm.dbih = (const float*)d_in[10];
  prm.dbhh = (const float*)d_in[11];
  prm.attW = (const float*)d_in[12];
  prm.outW = (const float*)d_in[13];
  prm.outb = (const float*)d_in[14];
  prm.vocW = (const float*)d_in[15];
  prm.vocb = (const float*)d_in[16];
  prm.ws   = (char*)d_ws;
  prm.out  = (float*)d_out;

  k_main<<<dim3(NWG), dim3(NT), SM_BYTES, stream>>>(prm);
}